// Round 2
// baseline (3628.948 us; speedup 1.0000x reference)
//
#include <hip/hip_runtime.h>
#include <cstdint>
#include <cstddef>

typedef unsigned short u16;
typedef unsigned int u32;
typedef float f32x4 __attribute__((ext_vector_type(4)));
typedef __bf16 bf16x8 __attribute__((ext_vector_type(8)));

__device__ inline u16 f32_to_bf16(float f) {
  u32 u = __float_as_uint(f);
  u = (u + 0x7FFFu + ((u >> 16) & 1u)) >> 16;
  return (u16)u;
}

#define GLD16(src, dst)                                                        \
  __builtin_amdgcn_global_load_lds(                                            \
      (const __attribute__((address_space(1))) u32*)(src),                     \
      (__attribute__((address_space(3))) u32*)(dst), 16, 0, 0)

#define SBAR() __builtin_amdgcn_s_barrier()
#define SETPRIO(x) __builtin_amdgcn_s_setprio(x)
#define WAIT_LGKM0()                                                           \
  do {                                                                         \
    asm volatile("s_waitcnt lgkmcnt(0)" ::: "memory");                         \
    __builtin_amdgcn_sched_barrier(0);                                         \
  } while (0)
#define MFMA16(a, b, c) __builtin_amdgcn_mfma_f32_16x16x32_bf16(a, b, c, 0, 0, 0)

// ---- 8-phase staging: one op = 512 thr x 16B = 128 rows x 64B (32 bf16 k-half)
// LDS linear byte d (within half-buffer) holds source k-byte (d&63)^((row&3)<<4)
// of row d>>6.  Read side applies the same XOR -> unswizzled data lands in regs.
__device__ inline void stage_one(const char* laneBase, long colByte,
                                 long strideB, int rowBase, u16* ldsHalf,
                                 int wave) {
  const char* src = laneBase + colByte + (long)rowBase * strideB;
  char* dst = (char*)ldsHalf + rowBase * 64 + wave * 1024;
  GLD16(src, dst);
}

// fragment read from a [R rows][32 k] half-buffer, 64B rows, swizzled
__device__ inline bf16x8 fragK(const u16* half, int row, int p) {
  const int byte = row * 64 + (((p ^ row) & 3) << 4);
  return *(const bf16x8*)((const char*)half + byte);
}

// ---------- x fp32 -> bf16 ----------
__global__ void k_convert_x(const float* __restrict__ x, u16* __restrict__ o) {
  const long i = (long)blockIdx.x * 256 + threadIdx.x;
  const float4 a = ((const float4*)x)[i * 2];
  const float4 b = ((const float4*)x)[i * 2 + 1];
  uint4 r;
  r.x = (u32)f32_to_bf16(a.x) | ((u32)f32_to_bf16(a.y) << 16);
  r.y = (u32)f32_to_bf16(a.z) | ((u32)f32_to_bf16(a.w) << 16);
  r.z = (u32)f32_to_bf16(b.x) | ((u32)f32_to_bf16(b.y) << 16);
  r.w = (u32)f32_to_bf16(b.z) | ((u32)f32_to_bf16(b.w) << 16);
  ((uint4*)o)[i] = r;
}

// ---------- dequant W[K][N] (int 0..15) -> out[N][K] bf16 (transposed) ------
__global__ __launch_bounds__(256) void k_dequant(const int* __restrict__ W,
                                                 const int* __restrict__ Z,
                                                 const float* __restrict__ S,
                                                 u16* __restrict__ out, int K,
                                                 int N) {
  __shared__ u16 ldsT[256 * 66];
  const int k0 = blockIdx.x * 64, n0 = blockIdx.y * 256;
  const int t = threadIdx.x;
  const int n4 = t & 63;
  const int kr = t >> 6;
  const int g = k0 >> 7;
  const int nb = n0 + n4 * 4;
  const int4 z4 = *(const int4*)(Z + (size_t)g * N + nb);
  const float4 s4 = *(const float4*)(S + (size_t)g * N + nb);
#pragma unroll
  for (int pass = 0; pass < 16; ++pass) {
    const int kl = kr + pass * 4;
    const int4 w4 = *(const int4*)(W + (size_t)(k0 + kl) * N + nb);
    ldsT[(n4 * 4 + 0) * 66 + kl] = f32_to_bf16((float)(w4.x - z4.x) * s4.x);
    ldsT[(n4 * 4 + 1) * 66 + kl] = f32_to_bf16((float)(w4.y - z4.y) * s4.y);
    ldsT[(n4 * 4 + 2) * 66 + kl] = f32_to_bf16((float)(w4.z - z4.z) * s4.z);
    ldsT[(n4 * 4 + 3) * 66 + kl] = f32_to_bf16((float)(w4.w - z4.w) * s4.w);
  }
  __syncthreads();
#pragma unroll
  for (int pass = 0; pass < 8; ++pass) {
    const int nl = pass * 32 + (t >> 3);
    const int kc = (t & 7) * 8;
    const u16* p = &ldsT[nl * 66 + kc];
    const u32 w0 = *(const u32*)(p + 0);
    const u32 w1 = *(const u32*)(p + 2);
    const u32 w2 = *(const u32*)(p + 4);
    const u32 w3 = *(const u32*)(p + 6);
    *(uint4*)(out + (size_t)(n0 + nl) * K + k0 + kc) =
        make_uint4(w0, w1, w2, w3);
  }
}

// ---------- fused gate/up GEMM, 8-phase schedule ----------
// X[8192][4096] bf16, WG/WU [14336][4096] bf16 (n-major), Hout[8192][14336] bf16
// BM=256 BN=128 BK=64; 8 waves (2x4): per-wave 128 rows x 32 cols x {G,U}.
__global__ __launch_bounds__(512, 2) void k_gemm_gu(
    const u16* __restrict__ X, const u16* __restrict__ WG,
    const u16* __restrict__ WU, u16* __restrict__ Hout) {
  __shared__ __align__(16) u16 lA[2][2][8192];  // [dbuf][kshalf][256r x 32k]
  __shared__ __align__(16) u16 lG[2][2][4096];  // [dbuf][kshalf][128r x 32k]
  __shared__ __align__(16) u16 lU[2][2][4096];
  const int NKT = 64;  // 4096 / 64
  const int m0 = blockIdx.x * 256, n0 = blockIdx.y * 128;
  const int tid = threadIdx.x, lane = tid & 63, wave = tid >> 6;
  const int p = lane >> 4, r16 = lane & 15;
  const int wr = wave >> 2, wc = wave & 3;

  // per-lane staging source bases (row + swizzled k-slot folded in)
  const int srow = wave * 16 + (lane >> 2);
  const int kb = (((lane & 3) ^ (lane >> 2)) & 3) << 4;
  const char* baA = (const char*)X + (long)(m0 + srow) * 8192 + kb;
  const char* baG = (const char*)WG + (long)(n0 + srow) * 8192 + kb;
  const char* baU = (const char*)WU + (long)(n0 + srow) * 8192 + kb;

#define ISS_A(kts, ksh, rb) \
  stage_one(baA, (long)(kts)*128 + (ksh)*64, 8192, rb, &lA[(kts)&1][ksh][0], wave)
#define ISS_G(kts, ksh) \
  stage_one(baG, (long)(kts)*128 + (ksh)*64, 8192, 0, &lG[(kts)&1][ksh][0], wave)
#define ISS_U(kts, ksh) \
  stage_one(baU, (long)(kts)*128 + (ksh)*64, 8192, 0, &lU[(kts)&1][ksh][0], wave)

  f32x4 aG[8][2], aU[8][2];
  const f32x4 zero = {0.f, 0.f, 0.f, 0.f};
#pragma unroll
  for (int i = 0; i < 8; ++i)
#pragma unroll
    for (int j = 0; j < 2; ++j) {
      aG[i][j] = zero;
      aU[i][j] = zero;
    }

  // prologue: ops s=0..13 (kt0 h0..7, kt1 h0..5)
  ISS_A(0, 0, 0); ISS_A(0, 0, 128); ISS_G(0, 0); ISS_U(0, 0);
  ISS_A(0, 1, 0); ISS_A(0, 1, 128); ISS_G(0, 1); ISS_U(0, 1);
  ISS_A(1, 0, 0); ISS_A(1, 0, 128); ISS_G(1, 0); ISS_U(1, 0);
  ISS_A(1, 1, 0); ISS_A(1, 1, 128);
  asm volatile("s_waitcnt vmcnt(6)" ::: "memory");  // kt0's 8 ops landed
  SBAR();

  for (int kt = 0; kt < NKT; ++kt) {
    const int b = kt & 1;
    const bool g1 = (kt + 1 < NKT), g2 = (kt + 2 < NKT);
#pragma unroll
    for (int ksh = 0; ksh < 2; ++ksh) {
      bf16x8 af[8], gf[2], uf[2];
      const u16* hA = &lA[b][ksh][0];
      const u16* hG = &lG[b][ksh][0];
      const u16* hU = &lU[b][ksh][0];
#pragma unroll
      for (int i = 0; i < 8; ++i)
        af[i] = fragK(hA, wr * 128 + i * 16 + r16, p);
#pragma unroll
      for (int j = 0; j < 2; ++j) {
        gf[j] = fragK(hG, wc * 32 + j * 16 + r16, p);
        uf[j] = fragK(hU, wc * 32 + j * 16 + r16, p);
      }
      // stage issue (global op order: see schedule derivation)
      if (ksh == 0) {
        if (g1) { ISS_G(kt + 1, 1); ISS_U(kt + 1, 1); }
      } else {
        if (g2) { ISS_G(kt + 2, 0); ISS_U(kt + 2, 0); }
      }
      SBAR();
      WAIT_LGKM0();
      SETPRIO(1);
#pragma unroll
      for (int i = 0; i < 8; ++i)
#pragma unroll
        for (int j = 0; j < 2; ++j) aG[i][j] = MFMA16(af[i], gf[j], aG[i][j]);
      SETPRIO(0);
      SBAR();
      // second phase of this k-slice: U MFMAs, register reuse (no ds_read)
      if (ksh == 0) {
        if (g2) { ISS_A(kt + 2, 0, 0); ISS_A(kt + 2, 0, 128); }
      } else {
        if (g2) { ISS_A(kt + 2, 1, 0); ISS_A(kt + 2, 1, 128); }
      }
      SBAR();
      SETPRIO(1);
#pragma unroll
      for (int i = 0; i < 8; ++i)
#pragma unroll
        for (int j = 0; j < 2; ++j) aU[i][j] = MFMA16(af[i], uf[j], aU[i][j]);
      SETPRIO(0);
      if (ksh == 1) {  // per-K-tile checkpoint: all of kt+1's ops landed
        if (kt < NKT - 2)
          asm volatile("s_waitcnt vmcnt(6)" ::: "memory");
        else if (kt == NKT - 2)
          asm volatile("s_waitcnt vmcnt(0)" ::: "memory");
      }
      SBAR();
    }
  }
#undef ISS_A
#undef ISS_G
#undef ISS_U

  // epilogue: silu(g)*u -> bf16.  C/D map: col=lane&15, row=(lane>>4)*4+reg.
#pragma unroll
  for (int i = 0; i < 8; ++i) {
    const int row = m0 + wr * 128 + i * 16 + p * 4;
#pragma unroll
    for (int j = 0; j < 2; ++j) {
      const int col = n0 + wc * 32 + j * 16 + r16;
      u16* dst = Hout + (size_t)row * 14336 + col;
#pragma unroll
      for (int r = 0; r < 4; ++r) {
        const float gv = aG[i][j][r], uv = aU[i][j][r];
        const float sv = gv / (1.f + __expf(-gv)) * uv;
        dst[(size_t)r * 14336] = f32_to_bf16(sv);
      }
    }
  }
}

// ---------- down GEMM, 8-phase schedule: out = h @ Wd (fp32 out) ----------
// Hin[8192][14336] bf16, WD[4096][14336] bf16 (n-major), Out[8192][4096] f32
// BM=BN=256 BK=64; 8 waves (2x4): per-wave 128 rows x 64 cols.
__global__ __launch_bounds__(512, 2) void k_gemm_down(
    const u16* __restrict__ Hin, const u16* __restrict__ WD,
    float* __restrict__ Out) {
  __shared__ __align__(16) u16 lA[2][2][8192];
  __shared__ __align__(16) u16 lB[2][2][8192];
  const int NKT = 224;  // 14336 / 64
  const int m0 = blockIdx.x * 256, n0 = blockIdx.y * 256;
  const int tid = threadIdx.x, lane = tid & 63, wave = tid >> 6;
  const int p = lane >> 4, r16 = lane & 15;
  const int wr = wave >> 2, wc = wave & 3;

  const int srow = wave * 16 + (lane >> 2);
  const int kb = (((lane & 3) ^ (lane >> 2)) & 3) << 4;
  const char* baA = (const char*)Hin + (long)(m0 + srow) * 28672 + kb;
  const char* baB = (const char*)WD + (long)(n0 + srow) * 28672 + kb;

#define ISS_A(kts, ksh, rb) \
  stage_one(baA, (long)(kts)*128 + (ksh)*64, 28672, rb, &lA[(kts)&1][ksh][0], wave)
#define ISS_B(kts, ksh, rb) \
  stage_one(baB, (long)(kts)*128 + (ksh)*64, 28672, rb, &lB[(kts)&1][ksh][0], wave)

  f32x4 acc[8][4];
  const f32x4 zero = {0.f, 0.f, 0.f, 0.f};
#pragma unroll
  for (int i = 0; i < 8; ++i)
#pragma unroll
    for (int j = 0; j < 4; ++j) acc[i][j] = zero;

  // prologue: kt0 h0..7, kt1 h0..5
  ISS_A(0, 0, 0); ISS_A(0, 0, 128); ISS_B(0, 0, 0); ISS_B(0, 0, 128);
  ISS_A(0, 1, 0); ISS_A(0, 1, 128); ISS_B(0, 1, 0); ISS_B(0, 1, 128);
  ISS_A(1, 0, 0); ISS_A(1, 0, 128); ISS_B(1, 0, 0); ISS_B(1, 0, 128);
  ISS_A(1, 1, 0); ISS_A(1, 1, 128);
  asm volatile("s_waitcnt vmcnt(6)" ::: "memory");
  SBAR();

  for (int kt = 0; kt < NKT; ++kt) {
    const int b = kt & 1;
    const bool g1 = (kt + 1 < NKT), g2 = (kt + 2 < NKT);
#pragma unroll
    for (int ksh = 0; ksh < 2; ++ksh) {
      bf16x8 af[8], bfr[4];
      const u16* hA = &lA[b][ksh][0];
      const u16* hB = &lB[b][ksh][0];
#pragma unroll
      for (int i = 0; i < 8; ++i)
        af[i] = fragK(hA, wr * 128 + i * 16 + r16, p);
#pragma unroll
      for (int j = 0; j < 4; ++j)
        bfr[j] = fragK(hB, wc * 64 + j * 16 + r16, p);
      if (ksh == 0) {
        if (g1) { ISS_B(kt + 1, 1, 0); ISS_B(kt + 1, 1, 128); }
      } else {
        if (g2) { ISS_B(kt + 2, 0, 0); ISS_B(kt + 2, 0, 128); }
      }
      SBAR();
      WAIT_LGKM0();
      SETPRIO(1);
#pragma unroll
      for (int i = 0; i < 8; ++i)
#pragma unroll
        for (int j = 0; j < 2; ++j)
          acc[i][j] = MFMA16(af[i], bfr[j], acc[i][j]);
      SETPRIO(0);
      SBAR();
      if (ksh == 0) {
        if (g2) { ISS_A(kt + 2, 0, 0); ISS_A(kt + 2, 0, 128); }
      } else {
        if (g2) { ISS_A(kt + 2, 1, 0); ISS_A(kt + 2, 1, 128); }
      }
      SBAR();
      SETPRIO(1);
#pragma unroll
      for (int i = 0; i < 8; ++i)
#pragma unroll
        for (int j = 2; j < 4; ++j)
          acc[i][j] = MFMA16(af[i], bfr[j], acc[i][j]);
      SETPRIO(0);
      if (ksh == 1) {
        if (kt < NKT - 2)
          asm volatile("s_waitcnt vmcnt(6)" ::: "memory");
        else if (kt == NKT - 2)
          asm volatile("s_waitcnt vmcnt(0)" ::: "memory");
      }
      SBAR();
    }
  }
#undef ISS_A
#undef ISS_B

#pragma unroll
  for (int i = 0; i < 8; ++i) {
    const int row = m0 + wr * 128 + i * 16 + p * 4;
#pragma unroll
    for (int j = 0; j < 4; ++j) {
      const int col = n0 + wc * 64 + j * 16 + r16;
      float* dst = Out + (size_t)row * 4096 + col;
#pragma unroll
      for (int r = 0; r < 4; ++r) dst[(size_t)r * 4096] = acc[i][j][r];
    }
  }
}

// ---------- sentinel fill (ws too small diagnostic) ----------
__global__ void k_fill(float* o, long n, float v) {
  const long i = (long)blockIdx.x * 256 + threadIdx.x;
  if (i < n) o[i] = v;
}

extern "C" void kernel_launch(void* const* d_in, const int* in_sizes, int n_in,
                              void* d_out, int out_size, void* d_ws,
                              size_t ws_size, hipStream_t stream) {
  const float* x = (const float*)d_in[0];
  const int* gw = (const int*)d_in[1];
  const int* gz = (const int*)d_in[2];
  const float* gs = (const float*)d_in[3];
  const int* uw = (const int*)d_in[4];
  const int* uz = (const int*)d_in[5];
  const float* us = (const float*)d_in[6];
  const int* dw = (const int*)d_in[7];
  const int* dz = (const int*)d_in[8];
  const float* dsc = (const float*)d_in[9];
  float* out = (float*)d_out;

  const size_t NX = 33554432UL, NW = 58720256UL;
  const size_t need = 2UL * (NX + 3UL * NW + 117440512UL);
  if (ws_size < need) {
    k_fill<<<(out_size + 255) / 256, 256, 0, stream>>>(out, out_size, 1.0e6f);
    return;
  }
  u16* wsx = (u16*)d_ws;
  u16* wgq = wsx + NX;
  u16* wuq = wgq + NW;
  u16* wdq = wuq + NW;
  u16* wh = wdq + NW;

  k_convert_x<<<16384, 256, 0, stream>>>(x, wsx);
  dim3 dq1(64, 56);
  k_dequant<<<dq1, 256, 0, stream>>>(gw, gz, gs, wgq, 4096, 14336);
  k_dequant<<<dq1, 256, 0, stream>>>(uw, uz, us, wuq, 4096, 14336);
  dim3 dq2(224, 16);
  k_dequant<<<dq2, 256, 0, stream>>>(dw, dz, dsc, wdq, 14336, 4096);
  dim3 g1(32, 112);
  k_gemm_gu<<<g1, 512, 0, stream>>>(wsx, wgq, wuq, wh);
  dim3 g2(32, 16);
  k_gemm_down<<<g2, 512, 0, stream>>>(wh, wdq, out);
}

// Round 3
// 3342.170 us; speedup vs baseline: 1.0858x; 1.0858x over previous
//
#include <hip/hip_runtime.h>
#include <cstdint>
#include <cstddef>

typedef unsigned short u16;
typedef unsigned int u32;
typedef float f32x4 __attribute__((ext_vector_type(4)));
typedef __bf16 bf16x8 __attribute__((ext_vector_type(8)));

__device__ inline u16 f32_to_bf16(float f) {
  u32 u = __float_as_uint(f);
  u = (u + 0x7FFFu + ((u >> 16) & 1u)) >> 16;
  return (u16)u;
}

#define GLD16(src, dst)                                                        \
  __builtin_amdgcn_global_load_lds(                                            \
      (const __attribute__((address_space(1))) u32*)(src),                     \
      (__attribute__((address_space(3))) u32*)(dst), 16, 0, 0)

#define SBAR() __builtin_amdgcn_s_barrier()
#define SETPRIO(x) __builtin_amdgcn_s_setprio(x)
#define WAIT_LGKM0()                                                           \
  do {                                                                         \
    asm volatile("s_waitcnt lgkmcnt(0)" ::: "memory");                         \
    __builtin_amdgcn_sched_barrier(0);                                         \
  } while (0)
#define MFMA16(a, b, c) __builtin_amdgcn_mfma_f32_16x16x32_bf16(a, b, c, 0, 0, 0)

// ---- R1-proven tile layout: [rows][64 bf16] = 128B rows.
// LDS byte d holds global k-byte (d&127)^((row&7)<<4) of row d>>7. 0-conflict
// on both write (linear 1KB/wave gld_lds) and fragment read (PMC, round 1).
// One staging op = 512 thr x 16B = 8KB = 64 rows.
__device__ inline void stage_op(const char* src, void* ldsBase, int rowBase,
                                int wave) {
  GLD16(src, (char*)ldsBase + rowBase * 128 + wave * 1024);
}

__device__ inline bf16x8 fragK(const u16* tile, int row, int ks, int p) {
  const int byte = row * 128 + (((ks << 6) + (p << 4)) ^ ((row & 7) << 4));
  return *(const bf16x8*)((const char*)tile + byte);
}

// ---------- x fp32 -> bf16 ----------
__global__ void k_convert_x(const float* __restrict__ x, u16* __restrict__ o) {
  const long i = (long)blockIdx.x * 256 + threadIdx.x;
  const float4 a = ((const float4*)x)[i * 2];
  const float4 b = ((const float4*)x)[i * 2 + 1];
  uint4 r;
  r.x = (u32)f32_to_bf16(a.x) | ((u32)f32_to_bf16(a.y) << 16);
  r.y = (u32)f32_to_bf16(a.z) | ((u32)f32_to_bf16(a.w) << 16);
  r.z = (u32)f32_to_bf16(b.x) | ((u32)f32_to_bf16(b.y) << 16);
  r.w = (u32)f32_to_bf16(b.z) | ((u32)f32_to_bf16(b.w) << 16);
  ((uint4*)o)[i] = r;
}

// ---------- dequant W[K][N] (int 0..15) -> out[N][K] bf16 (transposed) ------
__global__ __launch_bounds__(256) void k_dequant(const int* __restrict__ W,
                                                 const int* __restrict__ Z,
                                                 const float* __restrict__ S,
                                                 u16* __restrict__ out, int K,
                                                 int N) {
  __shared__ u16 ldsT[256 * 66];
  const int k0 = blockIdx.x * 64, n0 = blockIdx.y * 256;
  const int t = threadIdx.x;
  const int n4 = t & 63;
  const int kr = t >> 6;
  const int g = k0 >> 7;
  const int nb = n0 + n4 * 4;
  const int4 z4 = *(const int4*)(Z + (size_t)g * N + nb);
  const float4 s4 = *(const float4*)(S + (size_t)g * N + nb);
#pragma unroll
  for (int pass = 0; pass < 16; ++pass) {
    const int kl = kr + pass * 4;
    const int4 w4 = *(const int4*)(W + (size_t)(k0 + kl) * N + nb);
    ldsT[(n4 * 4 + 0) * 66 + kl] = f32_to_bf16((float)(w4.x - z4.x) * s4.x);
    ldsT[(n4 * 4 + 1) * 66 + kl] = f32_to_bf16((float)(w4.y - z4.y) * s4.y);
    ldsT[(n4 * 4 + 2) * 66 + kl] = f32_to_bf16((float)(w4.z - z4.z) * s4.z);
    ldsT[(n4 * 4 + 3) * 66 + kl] = f32_to_bf16((float)(w4.w - z4.w) * s4.w);
  }
  __syncthreads();
#pragma unroll
  for (int pass = 0; pass < 8; ++pass) {
    const int nl = pass * 32 + (t >> 3);
    const int kc = (t & 7) * 8;
    const u16* p = &ldsT[nl * 66 + kc];
    const u32 w0 = *(const u32*)(p + 0);
    const u32 w1 = *(const u32*)(p + 2);
    const u32 w2 = *(const u32*)(p + 4);
    const u32 w3 = *(const u32*)(p + 6);
    *(uint4*)(out + (size_t)(n0 + nl) * K + k0 + kc) =
        make_uint4(w0, w1, w2, w3);
  }
}

// ---------- fused gate/up GEMM, 4-phase counted-vmcnt schedule ----------
// X[8192][4096] bf16, WG/WU [14336][4096] bf16 (n-major), Hout[8192][14336]
// BM=256 BN=128 BK=64; 8 waves (2x4): per-wave 128 rows x 32 cols x {G,U}.
__global__ __launch_bounds__(512, 2) void k_gemm_gu(
    const u16* __restrict__ X, const u16* __restrict__ WG,
    const u16* __restrict__ WU, u16* __restrict__ Hout) {
  __shared__ __align__(16) u16 lA[2][16384];  // 2 x 256 rows x 64 k
  __shared__ __align__(16) u16 lG[2][8192];   // 2 x 128 rows x 64 k
  __shared__ __align__(16) u16 lU[2][8192];
  const int NKT = 64;
  const int m0 = blockIdx.x * 256, n0 = blockIdx.y * 128;
  const int tid = threadIdx.x, lane = tid & 63, wave = tid >> 6;
  const int p = lane >> 4, r16 = lane & 15;
  const int wr = wave >> 2, wc = wave & 3;

  const int srow = tid >> 3;                       // 0..63
  const int skb = (((tid ^ (tid >> 3)) & 7) << 4); // pre-swizzled k-byte
  const char* baA = (const char*)X + (long)(m0 + srow) * 8192 + skb;
  const char* baG = (const char*)WG + (long)(n0 + srow) * 8192 + skb;
  const char* baU = (const char*)WU + (long)(n0 + srow) * 8192 + skb;

#define ISS_A(kt2, rb) \
  stage_op(baA + (long)(rb) * 8192 + (long)(kt2) * 128, lA[(kt2) & 1], rb, wave)
#define ISS_G(kt2, rb) \
  stage_op(baG + (long)(rb) * 8192 + (long)(kt2) * 128, lG[(kt2) & 1], rb, wave)
#define ISS_U(kt2, rb) \
  stage_op(baU + (long)(rb) * 8192 + (long)(kt2) * 128, lU[(kt2) & 1], rb, wave)

  f32x4 aG[8][2], aU[8][2];
  const f32x4 zero = {0.f, 0.f, 0.f, 0.f};
#pragma unroll
  for (int i = 0; i < 8; ++i)
#pragma unroll
    for (int j = 0; j < 2; ++j) {
      aG[i][j] = zero;
      aU[i][j] = zero;
    }

  // prologue: stage kt0 (8 ops) + kt1 (8 ops); wait for kt0
  ISS_A(0, 0); ISS_A(0, 64); ISS_A(0, 128); ISS_A(0, 192);
  ISS_G(0, 0); ISS_G(0, 64); ISS_U(0, 0); ISS_U(0, 64);
  ISS_A(1, 0); ISS_A(1, 64); ISS_A(1, 128); ISS_A(1, 192);
  ISS_G(1, 0); ISS_G(1, 64); ISS_U(1, 0); ISS_U(1, 64);
  asm volatile("s_waitcnt vmcnt(8)" ::: "memory");
  SBAR();

  for (int kt = 0; kt < NKT; ++kt) {
    const int b = kt & 1;
    const u16* hA = lA[b];
    const u16* hG = lG[b];
    const u16* hU = lU[b];
    bf16x8 af[2][4], gf[2][2], uf[2][2];
    // ---- P0: A(i0..3) + G frags; MFMA aG i0..3 ----
#pragma unroll
    for (int ks = 0; ks < 2; ++ks) {
#pragma unroll
      for (int ii = 0; ii < 4; ++ii)
        af[ks][ii] = fragK(hA, wr * 128 + ii * 16 + r16, ks, p);
#pragma unroll
      for (int j = 0; j < 2; ++j)
        gf[ks][j] = fragK(hG, wc * 32 + j * 16 + r16, ks, p);
    }
    SBAR();
    WAIT_LGKM0();
    SETPRIO(1);
#pragma unroll
    for (int ks = 0; ks < 2; ++ks)
#pragma unroll
      for (int ii = 0; ii < 4; ++ii)
#pragma unroll
        for (int j = 0; j < 2; ++j)
          aG[ii][j] = MFMA16(af[ks][ii], gf[ks][j], aG[ii][j]);
    SETPRIO(0);
    SBAR();
    // ---- P1: U frags; MFMA aU i0..3 ----
#pragma unroll
    for (int ks = 0; ks < 2; ++ks)
#pragma unroll
      for (int j = 0; j < 2; ++j)
        uf[ks][j] = fragK(hU, wc * 32 + j * 16 + r16, ks, p);
    SBAR();
    WAIT_LGKM0();
    SETPRIO(1);
#pragma unroll
    for (int ks = 0; ks < 2; ++ks)
#pragma unroll
      for (int ii = 0; ii < 4; ++ii)
#pragma unroll
        for (int j = 0; j < 2; ++j)
          aU[ii][j] = MFMA16(af[ks][ii], uf[ks][j], aU[ii][j]);
    SETPRIO(0);
    SBAR();
    // ---- P2: A(i4..7) frags (last read of buf b); MFMA aG i4..7 ----
#pragma unroll
    for (int ks = 0; ks < 2; ++ks)
#pragma unroll
      for (int ii = 0; ii < 4; ++ii)
        af[ks][ii] = fragK(hA, wr * 128 + 64 + ii * 16 + r16, ks, p);
    SBAR();
    WAIT_LGKM0();
    SETPRIO(1);
#pragma unroll
    for (int ks = 0; ks < 2; ++ks)
#pragma unroll
      for (int ii = 0; ii < 4; ++ii)
#pragma unroll
        for (int j = 0; j < 2; ++j)
          aG[4 + ii][j] = MFMA16(af[ks][ii], gf[ks][j], aG[4 + ii][j]);
    SETPRIO(0);
    SBAR();
    // ---- P3: prefetch kt+2 into buf b (all reads of b drained); MFMA aU ----
    if (kt + 2 < NKT) {
      ISS_A(kt + 2, 0); ISS_A(kt + 2, 64);
      ISS_A(kt + 2, 128); ISS_A(kt + 2, 192);
      ISS_G(kt + 2, 0); ISS_G(kt + 2, 64);
      ISS_U(kt + 2, 0); ISS_U(kt + 2, 64);
    }
    SBAR();
    SETPRIO(1);
#pragma unroll
    for (int ks = 0; ks < 2; ++ks)
#pragma unroll
      for (int ii = 0; ii < 4; ++ii)
#pragma unroll
        for (int j = 0; j < 2; ++j)
          aU[4 + ii][j] = MFMA16(af[ks][ii], uf[ks][j], aU[4 + ii][j]);
    SETPRIO(0);
    if (kt < NKT - 2)
      asm volatile("s_waitcnt vmcnt(8)" ::: "memory");  // kt+1 landed
    else if (kt == NKT - 2)
      asm volatile("s_waitcnt vmcnt(0)" ::: "memory");
    SBAR();
  }
#undef ISS_A
#undef ISS_G
#undef ISS_U

  // epilogue: silu(g)*u -> bf16. C/D map: col=lane&15, row=(lane>>4)*4+reg.
#pragma unroll
  for (int i = 0; i < 8; ++i) {
    const int row = m0 + wr * 128 + i * 16 + p * 4;
#pragma unroll
    for (int j = 0; j < 2; ++j) {
      const int col = n0 + wc * 32 + j * 16 + r16;
      u16* dst = Hout + (size_t)row * 14336 + col;
#pragma unroll
      for (int r = 0; r < 4; ++r) {
        const float gv = aG[i][j][r], uv = aU[i][j][r];
        const float sv = gv / (1.f + __expf(-gv)) * uv;
        dst[(size_t)r * 14336] = f32_to_bf16(sv);
      }
    }
  }
}

// ---------- down GEMM, 4-phase schedule: out = h @ Wd (fp32 out) ----------
// Hin[8192][14336] bf16, WD[4096][14336] bf16 (n-major), Out[8192][4096] f32
// BM=BN=256 BK=64; 8 waves (2x4): per-wave 128 rows x 64 cols.
__global__ __launch_bounds__(512, 2) void k_gemm_down(
    const u16* __restrict__ Hin, const u16* __restrict__ WD,
    float* __restrict__ Out) {
  __shared__ __align__(16) u16 lA[2][16384];
  __shared__ __align__(16) u16 lB[2][16384];
  const int NKT = 224;
  const int m0 = blockIdx.x * 256, n0 = blockIdx.y * 256;
  const int tid = threadIdx.x, lane = tid & 63, wave = tid >> 6;
  const int p = lane >> 4, r16 = lane & 15;
  const int wr = wave >> 2, wc = wave & 3;

  const int srow = tid >> 3;
  const int skb = (((tid ^ (tid >> 3)) & 7) << 4);
  const char* baA = (const char*)Hin + (long)(m0 + srow) * 28672 + skb;
  const char* baB = (const char*)WD + (long)(n0 + srow) * 28672 + skb;

#define ISS_A(kt2, rb) \
  stage_op(baA + (long)(rb) * 28672 + (long)(kt2) * 128, lA[(kt2) & 1], rb, wave)
#define ISS_B(kt2, rb) \
  stage_op(baB + (long)(rb) * 28672 + (long)(kt2) * 128, lB[(kt2) & 1], rb, wave)

  f32x4 acc[8][4];
  const f32x4 zero = {0.f, 0.f, 0.f, 0.f};
#pragma unroll
  for (int i = 0; i < 8; ++i)
#pragma unroll
    for (int j = 0; j < 4; ++j) acc[i][j] = zero;

  ISS_A(0, 0); ISS_A(0, 64); ISS_A(0, 128); ISS_A(0, 192);
  ISS_B(0, 0); ISS_B(0, 64); ISS_B(0, 128); ISS_B(0, 192);
  ISS_A(1, 0); ISS_A(1, 64); ISS_A(1, 128); ISS_A(1, 192);
  ISS_B(1, 0); ISS_B(1, 64); ISS_B(1, 128); ISS_B(1, 192);
  asm volatile("s_waitcnt vmcnt(8)" ::: "memory");
  SBAR();

  for (int kt = 0; kt < NKT; ++kt) {
    const int b = kt & 1;
    const u16* hA = lA[b];
    const u16* hB = lB[b];
    bf16x8 af[2][4], bfr[2][4];
    // ---- P0: A(i0..3) + B(j0..1); MFMA i0..3 x j0..1 ----
#pragma unroll
    for (int ks = 0; ks < 2; ++ks) {
#pragma unroll
      for (int ii = 0; ii < 4; ++ii)
        af[ks][ii] = fragK(hA, wr * 128 + ii * 16 + r16, ks, p);
#pragma unroll
      for (int j = 0; j < 2; ++j)
        bfr[ks][j] = fragK(hB, wc * 64 + j * 16 + r16, ks, p);
    }
    SBAR();
    WAIT_LGKM0();
    SETPRIO(1);
#pragma unroll
    for (int ks = 0; ks < 2; ++ks)
#pragma unroll
      for (int ii = 0; ii < 4; ++ii)
#pragma unroll
        for (int j = 0; j < 2; ++j)
          acc[ii][j] = MFMA16(af[ks][ii], bfr[ks][j], acc[ii][j]);
    SETPRIO(0);
    SBAR();
    // ---- P1: B(j2..3); MFMA i0..3 x j2..3 ----
#pragma unroll
    for (int ks = 0; ks < 2; ++ks)
#pragma unroll
      for (int j = 2; j < 4; ++j)
        bfr[ks][j] = fragK(hB, wc * 64 + j * 16 + r16, ks, p);
    SBAR();
    WAIT_LGKM0();
    SETPRIO(1);
#pragma unroll
    for (int ks = 0; ks < 2; ++ks)
#pragma unroll
      for (int ii = 0; ii < 4; ++ii)
#pragma unroll
        for (int j = 2; j < 4; ++j)
          acc[ii][j] = MFMA16(af[ks][ii], bfr[ks][j], acc[ii][j]);
    SETPRIO(0);
    SBAR();
    // ---- P2: A(i4..7) (last read of buf b); MFMA i4..7 x j0..1 ----
#pragma unroll
    for (int ks = 0; ks < 2; ++ks)
#pragma unroll
      for (int ii = 0; ii < 4; ++ii)
        af[ks][ii] = fragK(hA, wr * 128 + 64 + ii * 16 + r16, ks, p);
    SBAR();
    WAIT_LGKM0();
    SETPRIO(1);
#pragma unroll
    for (int ks = 0; ks < 2; ++ks)
#pragma unroll
      for (int ii = 0; ii < 4; ++ii)
#pragma unroll
        for (int j = 0; j < 2; ++j)
          acc[4 + ii][j] = MFMA16(af[ks][ii], bfr[ks][j], acc[4 + ii][j]);
    SETPRIO(0);
    SBAR();
    // ---- P3: prefetch kt+2; MFMA i4..7 x j2..3 ----
    if (kt + 2 < NKT) {
      ISS_A(kt + 2, 0); ISS_A(kt + 2, 64);
      ISS_A(kt + 2, 128); ISS_A(kt + 2, 192);
      ISS_B(kt + 2, 0); ISS_B(kt + 2, 64);
      ISS_B(kt + 2, 128); ISS_B(kt + 2, 192);
    }
    SBAR();
    SETPRIO(1);
#pragma unroll
    for (int ks = 0; ks < 2; ++ks)
#pragma unroll
      for (int ii = 0; ii < 4; ++ii)
#pragma unroll
        for (int j = 2; j < 4; ++j)
          acc[4 + ii][j] = MFMA16(af[ks][ii], bfr[ks][j], acc[4 + ii][j]);
    SETPRIO(0);
    if (kt < NKT - 2)
      asm volatile("s_waitcnt vmcnt(8)" ::: "memory");
    else if (kt == NKT - 2)
      asm volatile("s_waitcnt vmcnt(0)" ::: "memory");
    SBAR();
  }
#undef ISS_A
#undef ISS_B

#pragma unroll
  for (int i = 0; i < 8; ++i) {
    const int row = m0 + wr * 128 + i * 16 + p * 4;
#pragma unroll
    for (int j = 0; j < 4; ++j) {
      const int col = n0 + wc * 64 + j * 16 + r16;
      float* dst = Out + (size_t)row * 4096 + col;
#pragma unroll
      for (int r = 0; r < 4; ++r) dst[(size_t)r * 4096] = acc[i][j][r];
    }
  }
}

// ---------- sentinel fill (ws too small diagnostic) ----------
__global__ void k_fill(float* o, long n, float v) {
  const long i = (long)blockIdx.x * 256 + threadIdx.x;
  if (i < n) o[i] = v;
}

extern "C" void kernel_launch(void* const* d_in, const int* in_sizes, int n_in,
                              void* d_out, int out_size, void* d_ws,
                              size_t ws_size, hipStream_t stream) {
  const float* x = (const float*)d_in[0];
  const int* gw = (const int*)d_in[1];
  const int* gz = (const int*)d_in[2];
  const float* gs = (const float*)d_in[3];
  const int* uw = (const int*)d_in[4];
  const int* uz = (const int*)d_in[5];
  const float* us = (const float*)d_in[6];
  const int* dw = (const int*)d_in[7];
  const int* dz = (const int*)d_in[8];
  const float* dsc = (const float*)d_in[9];
  float* out = (float*)d_out;

  const size_t NX = 33554432UL, NW = 58720256UL;
  const size_t need = 2UL * (NX + 3UL * NW + 117440512UL);
  if (ws_size < need) {
    k_fill<<<(out_size + 255) / 256, 256, 0, stream>>>(out, out_size, 1.0e6f);
    return;
  }
  u16* wsx = (u16*)d_ws;
  u16* wgq = wsx + NX;
  u16* wuq = wgq + NW;
  u16* wdq = wuq + NW;
  u16* wh = wdq + NW;

  k_convert_x<<<16384, 256, 0, stream>>>(x, wsx);
  dim3 dq1(64, 56);
  k_dequant<<<dq1, 256, 0, stream>>>(gw, gz, gs, wgq, 4096, 14336);
  k_dequant<<<dq1, 256, 0, stream>>>(uw, uz, us, wuq, 4096, 14336);
  dim3 dq2(224, 16);
  k_dequant<<<dq2, 256, 0, stream>>>(dw, dz, dsc, wdq, 14336, 4096);
  dim3 g1(32, 112);
  k_gemm_gu<<<g1, 512, 0, stream>>>(wsx, wgq, wuq, wh);
  dim3 g2(32, 16);
  k_gemm_down<<<g2, 512, 0, stream>>>(wh, wdq, out);
}

// Round 4
// 2577.295 us; speedup vs baseline: 1.4080x; 1.2968x over previous
//
#include <hip/hip_runtime.h>
#include <cstdint>
#include <cstddef>

typedef unsigned short u16;
typedef unsigned int u32;
typedef float f32x4 __attribute__((ext_vector_type(4)));
typedef __bf16 bf16x8 __attribute__((ext_vector_type(8)));

__device__ inline u16 f32_to_bf16(float f) {
  u32 u = __float_as_uint(f);
  u = (u + 0x7FFFu + ((u >> 16) & 1u)) >> 16;
  return (u16)u;
}

#define GLD16(src, dst)                                                        \
  __builtin_amdgcn_global_load_lds(                                            \
      (const __attribute__((address_space(1))) u32*)(src),                     \
      (__attribute__((address_space(3))) u32*)(dst), 16, 0, 0)

#define SBAR() __builtin_amdgcn_s_barrier()
#define SETPRIO(x) __builtin_amdgcn_s_setprio(x)
#define WAIT_LGKM0()                                                           \
  do {                                                                         \
    asm volatile("s_waitcnt lgkmcnt(0)" ::: "memory");                         \
    __builtin_amdgcn_sched_barrier(0);                                         \
  } while (0)
#define WAITV(N) asm volatile("s_waitcnt vmcnt(" #N ")" ::: "memory")
#define MFMA16(a, b, c) __builtin_amdgcn_mfma_f32_16x16x32_bf16(a, b, c, 0, 0, 0)

// ---- R1-proven tile layout: [rows][64 bf16] = 128B rows.
// LDS byte d holds global k-byte (d&127)^((row&7)<<4) of row d>>7. 0-conflict
// on write (linear 1KB/wave gld_lds) and fragment read (PMC, rounds 1,3).
// One staging op = 512 thr x 16B = 8KB = 64 rows.
__device__ inline void stage_op(const char* src, void* ldsBase, int rowBase,
                                int wave) {
  GLD16(src, (char*)ldsBase + rowBase * 128 + wave * 1024);
}

__device__ inline bf16x8 fragK(const u16* tile, int row, int ks, int p) {
  const int byte = row * 128 + (((ks << 6) + (p << 4)) ^ ((row & 7) << 4));
  return *(const bf16x8*)((const char*)tile + byte);
}

// ---------- x fp32 -> bf16 ----------
__global__ void k_convert_x(const float* __restrict__ x, u16* __restrict__ o) {
  const long i = (long)blockIdx.x * 256 + threadIdx.x;
  const float4 a = ((const float4*)x)[i * 2];
  const float4 b = ((const float4*)x)[i * 2 + 1];
  uint4 r;
  r.x = (u32)f32_to_bf16(a.x) | ((u32)f32_to_bf16(a.y) << 16);
  r.y = (u32)f32_to_bf16(a.z) | ((u32)f32_to_bf16(a.w) << 16);
  r.z = (u32)f32_to_bf16(b.x) | ((u32)f32_to_bf16(b.y) << 16);
  r.w = (u32)f32_to_bf16(b.z) | ((u32)f32_to_bf16(b.w) << 16);
  ((uint4*)o)[i] = r;
}

// ---------- dequant W[K][N] (int 0..15) -> out[N][K] bf16 (transposed) ------
__global__ __launch_bounds__(256) void k_dequant(const int* __restrict__ W,
                                                 const int* __restrict__ Z,
                                                 const float* __restrict__ S,
                                                 u16* __restrict__ out, int K,
                                                 int N) {
  __shared__ u16 ldsT[256 * 66];
  const int k0 = blockIdx.x * 64, n0 = blockIdx.y * 256;
  const int t = threadIdx.x;
  const int n4 = t & 63;
  const int kr = t >> 6;
  const int g = k0 >> 7;
  const int nb = n0 + n4 * 4;
  const int4 z4 = *(const int4*)(Z + (size_t)g * N + nb);
  const float4 s4 = *(const float4*)(S + (size_t)g * N + nb);
#pragma unroll
  for (int pass = 0; pass < 16; ++pass) {
    const int kl = kr + pass * 4;
    const int4 w4 = *(const int4*)(W + (size_t)(k0 + kl) * N + nb);
    ldsT[(n4 * 4 + 0) * 66 + kl] = f32_to_bf16((float)(w4.x - z4.x) * s4.x);
    ldsT[(n4 * 4 + 1) * 66 + kl] = f32_to_bf16((float)(w4.y - z4.y) * s4.y);
    ldsT[(n4 * 4 + 2) * 66 + kl] = f32_to_bf16((float)(w4.z - z4.z) * s4.z);
    ldsT[(n4 * 4 + 3) * 66 + kl] = f32_to_bf16((float)(w4.w - z4.w) * s4.w);
  }
  __syncthreads();
#pragma unroll
  for (int pass = 0; pass < 8; ++pass) {
    const int nl = pass * 32 + (t >> 3);
    const int kc = (t & 7) * 8;
    const u16* p = &ldsT[nl * 66 + kc];
    const u32 w0 = *(const u32*)(p + 0);
    const u32 w1 = *(const u32*)(p + 2);
    const u32 w2 = *(const u32*)(p + 4);
    const u32 w3 = *(const u32*)(p + 6);
    *(uint4*)(out + (size_t)(n0 + nl) * K + k0 + kc) =
        make_uint4(w0, w1, w2, w3);
  }
}

// ---------- fused gate/up GEMM, 4-phase fine-interleaved schedule ----------
// X[8192][4096] bf16, WG/WU [14336][4096] bf16 (n-major), Hout[8192][14336]
// BM=256 BN=128 BK=64; 8 waves (2x4): per-wave 128 rows x 32 cols x {G,U}.
// Tile T's 8 staging ops issued 2/phase over [T-2.P3, T-1.P0, T-1.P1, T-1.P2]
// in first-consumed order [A0,A128 | G0,G64 | U0,U64 | A64,A192].
__global__ __launch_bounds__(512, 2) void k_gemm_gu(
    const u16* __restrict__ X, const u16* __restrict__ WG,
    const u16* __restrict__ WU, u16* __restrict__ Hout) {
  __shared__ __align__(16) u16 lA[2][16384];  // 2 x 256 rows x 64 k
  __shared__ __align__(16) u16 lG[2][8192];   // 2 x 128 rows x 64 k
  __shared__ __align__(16) u16 lU[2][8192];
  const int NKT = 64;
  const int m0 = blockIdx.x * 256, n0 = blockIdx.y * 128;
  const int tid = threadIdx.x, lane = tid & 63, wave = tid >> 6;
  const int p = lane >> 4, r16 = lane & 15;
  const int wr = wave >> 2, wc = wave & 3;

  const int srow = tid >> 3;                       // 0..63
  const int skb = (((tid ^ (tid >> 3)) & 7) << 4); // pre-swizzled k-byte
  const char* baA = (const char*)X + (long)(m0 + srow) * 8192 + skb;
  const char* baG = (const char*)WG + (long)(n0 + srow) * 8192 + skb;
  const char* baU = (const char*)WU + (long)(n0 + srow) * 8192 + skb;

#define ISS_A(kt2, rb) \
  stage_op(baA + (long)(rb) * 8192 + (long)(kt2) * 128, lA[(kt2) & 1], rb, wave)
#define ISS_G(kt2, rb) \
  stage_op(baG + (long)(rb) * 8192 + (long)(kt2) * 128, lG[(kt2) & 1], rb, wave)
#define ISS_U(kt2, rb) \
  stage_op(baU + (long)(rb) * 8192 + (long)(kt2) * 128, lU[(kt2) & 1], rb, wave)

  f32x4 aG[8][2], aU[8][2];
  const f32x4 zero = {0.f, 0.f, 0.f, 0.f};
#pragma unroll
  for (int i = 0; i < 8; ++i)
#pragma unroll
    for (int j = 0; j < 2; ++j) {
      aG[i][j] = zero;
      aU[i][j] = zero;
    }

  // prologue: kt0's 8 ops in consumed order + kt1's first pair; vmcnt(6)
  ISS_A(0, 0); ISS_A(0, 128); ISS_G(0, 0); ISS_G(0, 64);
  ISS_U(0, 0); ISS_U(0, 64); ISS_A(0, 64); ISS_A(0, 192);
  ISS_A(1, 0); ISS_A(1, 128);
  WAITV(6);
  SBAR();

  for (int kt = 0; kt < NKT; ++kt) {
    const int b = kt & 1;
    const u16* hA = lA[b];
    const u16* hG = lG[b];
    const u16* hU = lU[b];
    bf16x8 af[2][4], gf[2][2], uf[2][2];
    // ---- P0: read A(i0..3)+G; stage kt+1's G; MFMA aG i0..3 ----
#pragma unroll
    for (int ks = 0; ks < 2; ++ks) {
#pragma unroll
      for (int ii = 0; ii < 4; ++ii)
        af[ks][ii] = fragK(hA, wr * 128 + ii * 16 + r16, ks, p);
#pragma unroll
      for (int j = 0; j < 2; ++j)
        gf[ks][j] = fragK(hG, wc * 32 + j * 16 + r16, ks, p);
    }
    if (kt < NKT - 1) { ISS_G(kt + 1, 0); ISS_G(kt + 1, 64); }
    SBAR();
    WAIT_LGKM0();
    SETPRIO(1);
#pragma unroll
    for (int ks = 0; ks < 2; ++ks)
#pragma unroll
      for (int ii = 0; ii < 4; ++ii)
#pragma unroll
        for (int j = 0; j < 2; ++j)
          aG[ii][j] = MFMA16(af[ks][ii], gf[ks][j], aG[ii][j]);
    SETPRIO(0);
    if (kt < NKT - 1) WAITV(6); else WAITV(2);  // kt's U landed
    SBAR();
    // ---- P1: read U; stage kt+1's U; MFMA aU i0..3 ----
#pragma unroll
    for (int ks = 0; ks < 2; ++ks)
#pragma unroll
      for (int j = 0; j < 2; ++j)
        uf[ks][j] = fragK(hU, wc * 32 + j * 16 + r16, ks, p);
    if (kt < NKT - 1) { ISS_U(kt + 1, 0); ISS_U(kt + 1, 64); }
    SBAR();
    WAIT_LGKM0();
    SETPRIO(1);
#pragma unroll
    for (int ks = 0; ks < 2; ++ks)
#pragma unroll
      for (int ii = 0; ii < 4; ++ii)
#pragma unroll
        for (int j = 0; j < 2; ++j)
          aU[ii][j] = MFMA16(af[ks][ii], uf[ks][j], aU[ii][j]);
    SETPRIO(0);
    if (kt < NKT - 1) WAITV(6); else WAITV(0);  // kt's A64/A192 landed
    SBAR();
    // ---- P2: read A(i4..7) (last read of buf b); stage kt+1's A-late ----
#pragma unroll
    for (int ks = 0; ks < 2; ++ks)
#pragma unroll
      for (int ii = 0; ii < 4; ++ii)
        af[ks][ii] = fragK(hA, wr * 128 + 64 + ii * 16 + r16, ks, p);
    if (kt < NKT - 1) { ISS_A(kt + 1, 64); ISS_A(kt + 1, 192); }
    SBAR();
    WAIT_LGKM0();
    SETPRIO(1);
#pragma unroll
    for (int ks = 0; ks < 2; ++ks)
#pragma unroll
      for (int ii = 0; ii < 4; ++ii)
#pragma unroll
        for (int j = 0; j < 2; ++j)
          aG[4 + ii][j] = MFMA16(af[ks][ii], gf[ks][j], aG[4 + ii][j]);
    SETPRIO(0);
    SBAR();
    // ---- P3: stage kt+2's A-early into buf b (reads drained); MFMA aU ----
    if (kt < NKT - 2) { ISS_A(kt + 2, 0); ISS_A(kt + 2, 128); }
    SBAR();
    SETPRIO(1);
#pragma unroll
    for (int ks = 0; ks < 2; ++ks)
#pragma unroll
      for (int ii = 0; ii < 4; ++ii)
#pragma unroll
        for (int j = 0; j < 2; ++j)
          aU[4 + ii][j] = MFMA16(af[ks][ii], uf[ks][j], aU[4 + ii][j]);
    SETPRIO(0);
    if (kt < NKT - 2) WAITV(6);       // kt+1's first 4 landed
    else if (kt == NKT - 2) WAITV(4);
    SBAR();
  }
#undef ISS_A
#undef ISS_G
#undef ISS_U

  // epilogue: silu(g)*u -> bf16. C/D map: col=lane&15, row=(lane>>4)*4+reg.
#pragma unroll
  for (int i = 0; i < 8; ++i) {
    const int row = m0 + wr * 128 + i * 16 + p * 4;
#pragma unroll
    for (int j = 0; j < 2; ++j) {
      const int col = n0 + wc * 32 + j * 16 + r16;
      u16* dst = Hout + (size_t)row * 14336 + col;
#pragma unroll
      for (int r = 0; r < 4; ++r) {
        const float gv = aG[i][j][r], uv = aU[i][j][r];
        const float sv = gv / (1.f + __expf(-gv)) * uv;
        dst[(size_t)r * 14336] = f32_to_bf16(sv);
      }
    }
  }
}

// ---------- down GEMM, 4-phase fine-interleaved: out = h @ Wd (f32) ----------
// Hin[8192][14336] bf16, WD[4096][14336] bf16 (n-major), Out[8192][4096] f32
// BM=BN=256 BK=64; 8 waves (2x4): per-wave 128 rows x 64 cols.
// Tile T issue order [A0,A128 | B0,B64 | B128,B192 | A64,A192].
__global__ __launch_bounds__(512, 2) void k_gemm_down(
    const u16* __restrict__ Hin, const u16* __restrict__ WD,
    float* __restrict__ Out) {
  __shared__ __align__(16) u16 lA[2][16384];
  __shared__ __align__(16) u16 lB[2][16384];
  const int NKT = 224;
  const int m0 = blockIdx.x * 256, n0 = blockIdx.y * 256;
  const int tid = threadIdx.x, lane = tid & 63, wave = tid >> 6;
  const int p = lane >> 4, r16 = lane & 15;
  const int wr = wave >> 2, wc = wave & 3;

  const int srow = tid >> 3;
  const int skb = (((tid ^ (tid >> 3)) & 7) << 4);
  const char* baA = (const char*)Hin + (long)(m0 + srow) * 28672 + skb;
  const char* baB = (const char*)WD + (long)(n0 + srow) * 28672 + skb;

#define ISS_A(kt2, rb) \
  stage_op(baA + (long)(rb) * 28672 + (long)(kt2) * 128, lA[(kt2) & 1], rb, wave)
#define ISS_B(kt2, rb) \
  stage_op(baB + (long)(rb) * 28672 + (long)(kt2) * 128, lB[(kt2) & 1], rb, wave)

  f32x4 acc[8][4];
  const f32x4 zero = {0.f, 0.f, 0.f, 0.f};
#pragma unroll
  for (int i = 0; i < 8; ++i)
#pragma unroll
    for (int j = 0; j < 4; ++j) acc[i][j] = zero;

  // prologue: kt0's 8 in consumed order + kt1's first pair; vmcnt(4)
  ISS_A(0, 0); ISS_A(0, 128); ISS_B(0, 0); ISS_B(0, 64);
  ISS_B(0, 128); ISS_B(0, 192); ISS_A(0, 64); ISS_A(0, 192);
  ISS_A(1, 0); ISS_A(1, 128);
  WAITV(4);
  SBAR();

  for (int kt = 0; kt < NKT; ++kt) {
    const int b = kt & 1;
    const u16* hA = lA[b];
    const u16* hB = lB[b];
    bf16x8 af[2][4], bfr[2][4];
    // ---- P0: read A(i0..3)+B(j0..1); stage kt+1's B-early ----
#pragma unroll
    for (int ks = 0; ks < 2; ++ks) {
#pragma unroll
      for (int ii = 0; ii < 4; ++ii)
        af[ks][ii] = fragK(hA, wr * 128 + ii * 16 + r16, ks, p);
#pragma unroll
      for (int j = 0; j < 2; ++j)
        bfr[ks][j] = fragK(hB, wc * 64 + j * 16 + r16, ks, p);
    }
    if (kt < NKT - 1) { ISS_B(kt + 1, 0); ISS_B(kt + 1, 64); }
    SBAR();
    WAIT_LGKM0();
    SETPRIO(1);
#pragma unroll
    for (int ks = 0; ks < 2; ++ks)
#pragma unroll
      for (int ii = 0; ii < 4; ++ii)
#pragma unroll
        for (int j = 0; j < 2; ++j)
          acc[ii][j] = MFMA16(af[ks][ii], bfr[ks][j], acc[ii][j]);
    SETPRIO(0);
    SBAR();
    // ---- P1: read B(j2..3); stage kt+1's B-late ----
#pragma unroll
    for (int ks = 0; ks < 2; ++ks)
#pragma unroll
      for (int j = 2; j < 4; ++j)
        bfr[ks][j] = fragK(hB, wc * 64 + j * 16 + r16, ks, p);
    if (kt < NKT - 1) { ISS_B(kt + 1, 128); ISS_B(kt + 1, 192); }
    SBAR();
    WAIT_LGKM0();
    SETPRIO(1);
#pragma unroll
    for (int ks = 0; ks < 2; ++ks)
#pragma unroll
      for (int ii = 0; ii < 4; ++ii)
#pragma unroll
        for (int j = 2; j < 4; ++j)
          acc[ii][j] = MFMA16(af[ks][ii], bfr[ks][j], acc[ii][j]);
    SETPRIO(0);
    if (kt < NKT - 1) WAITV(6); else WAITV(0);  // kt's A64/A192 landed
    SBAR();
    // ---- P2: read A(i4..7) (last read of buf b); stage kt+1's A-late ----
#pragma unroll
    for (int ks = 0; ks < 2; ++ks)
#pragma unroll
      for (int ii = 0; ii < 4; ++ii)
        af[ks][ii] = fragK(hA, wr * 128 + 64 + ii * 16 + r16, ks, p);
    if (kt < NKT - 1) { ISS_A(kt + 1, 64); ISS_A(kt + 1, 192); }
    SBAR();
    WAIT_LGKM0();
    SETPRIO(1);
#pragma unroll
    for (int ks = 0; ks < 2; ++ks)
#pragma unroll
      for (int ii = 0; ii < 4; ++ii)
#pragma unroll
        for (int j = 0; j < 2; ++j)
          acc[4 + ii][j] = MFMA16(af[ks][ii], bfr[ks][j], acc[4 + ii][j]);
    SETPRIO(0);
    SBAR();
    // ---- P3: stage kt+2's A-early into buf b; MFMA i4..7 x j2..3 ----
    if (kt < NKT - 2) { ISS_A(kt + 2, 0); ISS_A(kt + 2, 128); }
    SBAR();
    SETPRIO(1);
#pragma unroll
    for (int ks = 0; ks < 2; ++ks)
#pragma unroll
      for (int ii = 0; ii < 4; ++ii)
#pragma unroll
        for (int j = 2; j < 4; ++j)
          acc[4 + ii][j] = MFMA16(af[ks][ii], bfr[ks][j], acc[4 + ii][j]);
    SETPRIO(0);
    if (kt < NKT - 2) WAITV(4);       // kt+1's first 6 landed
    else if (kt == NKT - 2) WAITV(2);
    SBAR();
  }
#undef ISS_A
#undef ISS_B

#pragma unroll
  for (int i = 0; i < 8; ++i) {
    const int row = m0 + wr * 128 + i * 16 + p * 4;
#pragma unroll
    for (int j = 0; j < 4; ++j) {
      const int col = n0 + wc * 64 + j * 16 + r16;
      float* dst = Out + (size_t)row * 4096 + col;
#pragma unroll
      for (int r = 0; r < 4; ++r) dst[(size_t)r * 4096] = acc[i][j][r];
    }
  }
}

// ---------- sentinel fill (ws too small diagnostic) ----------
__global__ void k_fill(float* o, long n, float v) {
  const long i = (long)blockIdx.x * 256 + threadIdx.x;
  if (i < n) o[i] = v;
}

extern "C" void kernel_launch(void* const* d_in, const int* in_sizes, int n_in,
                              void* d_out, int out_size, void* d_ws,
                              size_t ws_size, hipStream_t stream) {
  const float* x = (const float*)d_in[0];
  const int* gw = (const int*)d_in[1];
  const int* gz = (const int*)d_in[2];
  const float* gs = (const float*)d_in[3];
  const int* uw = (const int*)d_in[4];
  const int* uz = (const int*)d_in[5];
  const float* us = (const float*)d_in[6];
  const int* dw = (const int*)d_in[7];
  const int* dz = (const int*)d_in[8];
  const float* dsc = (const float*)d_in[9];
  float* out = (float*)d_out;

  const size_t NX = 33554432UL, NW = 58720256UL;
  const size_t need = 2UL * (NX + 3UL * NW + 117440512UL);
  if (ws_size < need) {
    k_fill<<<(out_size + 255) / 256, 256, 0, stream>>>(out, out_size, 1.0e6f);
    return;
  }
  u16* wsx = (u16*)d_ws;
  u16* wgq = wsx + NX;
  u16* wuq = wgq + NW;
  u16* wdq = wuq + NW;
  u16* wh = wdq + NW;

  k_convert_x<<<16384, 256, 0, stream>>>(x, wsx);
  dim3 dq1(64, 56);
  k_dequant<<<dq1, 256, 0, stream>>>(gw, gz, gs, wgq, 4096, 14336);
  k_dequant<<<dq1, 256, 0, stream>>>(uw, uz, us, wuq, 4096, 14336);
  dim3 dq2(224, 16);
  k_dequant<<<dq2, 256, 0, stream>>>(dw, dz, dsc, wdq, 14336, 4096);
  dim3 g1(32, 112);
  k_gemm_gu<<<g1, 512, 0, stream>>>(wsx, wgq, wuq, wh);
  dim3 g2(32, 16);
  k_gemm_down<<<g2, 512, 0, stream>>>(wh, wdq, out);
}